// Round 10
// baseline (102.476 us; speedup 1.0000x reference)
//
#include <hip/hip_runtime.h>
#include <cmath>

#define R_ROWS 1000
#define NCLS   81
#define REGW   (NCLS * 4)
#define SCORE_T 0.05f
#define NMS_T   0.5f
#define NEG_S  -1e9f
#define DETS   100
#define CLIP_V 4.135166556742356f   // log(1000/16)
#define MAXC   1000
#define SLOTS  1000                  // per-class klist region
#define NBLK_CLS 80                  // classes 1..80 -> blocks 0..79

#define CHUNK_R 128                  // rows staged in LDS per chunk
#define NCHUNK  8                    // ceil(1000/128)

#define NBINS    1024
#define CK_CAP   2560                // LDS key buffer (typ. K ~ 2000)
#define SURV_CAP 512                 // LDS survivor buffer (typ. Mc ~ 150)

// ---------- exact-order helpers (no FMA contraction: match numpy/XLA separate rounding) ----------

__device__ __forceinline__ float4 decode_clip(const float* __restrict__ prop,
                                              const float* __restrict__ reg,
                                              int r, int ccol, float wmax, float hmax) {
    float x1 = prop[r * 4 + 0], y1 = prop[r * 4 + 1];
    float x2 = prop[r * 4 + 2], y2 = prop[r * 4 + 3];
    float w  = __fadd_rn(__fsub_rn(x2, x1), 1.0f);
    float h  = __fadd_rn(__fsub_rn(y2, y1), 1.0f);
    float cx = __fadd_rn(x1, __fmul_rn(0.5f, w));
    float cy = __fadd_rn(y1, __fmul_rn(0.5f, h));
    const float* rr = reg + r * REGW + 4 * ccol;
    float dx = rr[0] / 10.0f;
    float dy = rr[1] / 10.0f;
    float dw = fminf(rr[2] / 5.0f, CLIP_V);
    float dh = fminf(rr[3] / 5.0f, CLIP_V);
    float pcx = __fadd_rn(__fmul_rn(dx, w), cx);
    float pcy = __fadd_rn(__fmul_rn(dy, h), cy);
    float pw  = __fmul_rn(expf(dw), w);
    float ph  = __fmul_rn(expf(dh), h);
    float ox1 = __fsub_rn(pcx, __fmul_rn(0.5f, pw));
    float oy1 = __fsub_rn(pcy, __fmul_rn(0.5f, ph));
    float ox2 = __fsub_rn(__fadd_rn(pcx, __fmul_rn(0.5f, pw)), 1.0f);
    float oy2 = __fsub_rn(__fadd_rn(pcy, __fmul_rn(0.5f, ph)), 1.0f);
    float4 o;
    o.x = fminf(fmaxf(ox1, 0.0f), wmax);
    o.y = fminf(fmaxf(oy1, 0.0f), hmax);
    o.z = fminf(fmaxf(ox2, 0.0f), wmax);
    o.w = fminf(fmaxf(oy2, 0.0f), hmax);
    return o;
}

__device__ __forceinline__ float iou_legacy(float ax1, float ay1, float ax2, float ay2,
                                            float bx1, float by1, float bx2, float by2) {
    float aw = __fadd_rn(__fsub_rn(ax2, ax1), 1.0f);
    float ah = __fadd_rn(__fsub_rn(ay2, ay1), 1.0f);
    float areaA = __fmul_rn(aw, ah);
    float bw = __fadd_rn(__fsub_rn(bx2, bx1), 1.0f);
    float bh = __fadd_rn(__fsub_rn(by2, by1), 1.0f);
    float areaB = __fmul_rn(bw, bh);
    float ltx = fmaxf(ax1, bx1), lty = fmaxf(ay1, by1);
    float rbx = fminf(ax2, bx2), rby = fminf(ay2, by2);
    float wx = fmaxf(__fadd_rn(__fsub_rn(rbx, ltx), 1.0f), 0.0f);
    float wy = fmaxf(__fadd_rn(__fsub_rn(rby, lty), 1.0f), 0.0f);
    float inter = __fmul_rn(wx, wy);
    float denom = __fsub_rn(__fadd_rn(areaA, areaB), inter);
    return inter / denom;
}

// monotone coarse bin of a positive float score (positive IEEE bits are order-preserving)
__device__ __forceinline__ int bin_of(float s) {
    int idx = (int)(__float_as_uint(s) >> 16) - 0x3D00;   // scores in (0.05,1] -> [76,640]
    return idx < 0 ? 0 : (idx > NBINS - 1 ? NBINS - 1 : idx);
}

__device__ __forceinline__ unsigned long long key_of(float s, unsigned f) {
    // (score desc, flat asc) as one monotone u64; valid keys nonzero (score > 0.05)
    return ((unsigned long long)__float_as_uint(s) << 32) | (unsigned long long)(~f);
}
__device__ __forceinline__ float key_score(unsigned long long k) {
    return __uint_as_float((unsigned)(k >> 32));
}
__device__ __forceinline__ int key_flat(unsigned long long k) {
    return (int)(~(unsigned)k);
}

// device-scope (sc1) coherent accesses. R7 lesson: NEVER spin-poll these (remote plain
// stores don't invalidate stale local-L2 lines). Safe usage here: all cross-block
// SIGNALING is atomic-RMW (always fresh at coherence point); sc1 data reads are
// one-shot, post-handoff, and hold deterministic (replay-invariant) values.
__device__ __forceinline__ void dev_store_u64(unsigned long long* p, unsigned long long v) {
    __hip_atomic_store(p, v, __ATOMIC_RELAXED, __HIP_MEMORY_SCOPE_AGENT);
}
__device__ __forceinline__ unsigned long long dev_load_u64(const unsigned long long* p) {
    return __hip_atomic_load(p, __ATOMIC_RELAXED, __HIP_MEMORY_SCOPE_AGENT);
}
__device__ __forceinline__ void dev_store_i32(int* p, int v) {
    __hip_atomic_store(p, v, __ATOMIC_RELAXED, __HIP_MEMORY_SCOPE_AGENT);
}

// upper-bound search: returns c with koff[c] <= g < koff[c+1]
__device__ __forceinline__ int find_class(const int* koff, int g) {
    int lo = 0, hi = NBLK_CLS;
    while (hi - lo > 1) { int mid = (lo + hi) >> 1; if (g >= koff[mid]) lo = mid; else hi = mid; }
    return lo;
}

// ---------- single kernel: 80 class blocks; last-finishing block (RMW) runs selection ----------

__global__ __launch_bounds__(256) void k_all(const float* __restrict__ logits,
                                             const float* __restrict__ reg,
                                             const float* __restrict__ prop,
                                             const int* __restrict__ piw,
                                             const int* __restrict__ pih,
                                             unsigned long long* __restrict__ klist,
                                             int* __restrict__ kcount,
                                             int* __restrict__ done,
                                             float* __restrict__ out) {
    // persistent class-phase LDS
    __shared__ float us[MAXC];  __shared__ int uidx[MAXC];
    __shared__ int cnt, sh_last;
    // small selector-phase statics
    __shared__ int   koff[NBLK_CLS + 1];
    __shared__ int   cs[256];
    __shared__ float sel_s[DETS]; __shared__ int sel_f[DETS];
    __shared__ int   sh_cut, sh_mcnt;
    // overlaid region (phases are strictly sequential, barriers between):
    //   phase 0/1: chunkf[128*81] f32                          = 41472 B
    //   phase 2-4: ss[1000] f32 | sidx[1000] i32 | bx4[1000][4] f32 | supp[1000] i32 = 28000 B
    //   selector : hist[1024] i32 | ck[CK_CAP] u64 | cks[SURV_CAP] u64               = 28672 B
    __shared__ __align__(16) char ubuf[41472];
    float* chunkf = (float*)ubuf;
    float* ss   = (float*)ubuf;
    int*   sidx = (int*)(ubuf + 4000);
    float (*bx4)[4] = (float(*)[4])(ubuf + 8000);
    int*   supp = (int*)(ubuf + 24000);
    int*   hist_s = (int*)ubuf;
    unsigned long long* ck  = (unsigned long long*)(ubuf + 4096);
    unsigned long long* cks = (unsigned long long*)(ubuf + 4096 + 8 * CK_CAP);

    const int cidx = blockIdx.x;       // 0..79
    const int ccol = cidx + 1;         // skip background class 0
    const int t    = threadIdx.x;
    const int lane = t & 63;
    const int wv   = t >> 6;
    const float wmax = (float)(*piw - 1);
    const float hmax = (float)(*pih - 1);

    if (t == 0) cnt = 0;
    __syncthreads();

    // ---- Phase 0+1 fused: LDS-staged softmax stats + score + threshold, per 128-row chunk.
    // Coalesced float4 global loads (fixes R6's 64-lines-per-load scatter); serial per-row
    // reduce from LDS (2-way bank alias = free; arithmetic order == R6, validated absmax 0).
    for (int c = 0; c < NCHUNK; ++c) {
        const int rb = c * CHUNK_R;
        int n = R_ROWS - rb; if (n > CHUNK_R) n = CHUNK_R;
        const int nw = n * NCLS;                       // always divisible by 4
        const float4* src = (const float4*)(logits + rb * NCLS);
        float4* dst = (float4*)chunkf;
        for (int i = t; i < (nw >> 2); i += 256) dst[i] = src[i];
        __syncthreads();
        if (t < n) {
            const float* row = chunkf + t * NCLS;
            float m = row[0];
            #pragma unroll 8
            for (int k = 1; k < NCLS; ++k) m = fmaxf(m, row[k]);
            float s = 0.0f;
            #pragma unroll 8
            for (int k = 0; k < NCLS; ++k) s = __fadd_rn(s, expf(__fsub_rn(row[k], m)));
            float sc = expf(__fsub_rn(row[ccol], m)) / s;
            if (sc > SCORE_T) {
                int p = atomicAdd(&cnt, 1);
                us[p] = sc; uidx[p] = rb + t;
            }
        }
        __syncthreads();   // chunkf reads done before next chunk overwrite
    }
    const int M = cnt;

    // ---- Phase 2a: exact rank sort (score desc, row asc) -> ss/sidx (overlays chunkf) ----
    for (int i = t; i < M; i += 256) {
        float si = us[i]; int ri = uidx[i];
        int rank = 0;
        for (int j = 0; j < M; j++) {
            float sj = us[j]; int rj = uidx[j];
            rank += (sj > si) || (sj == si && rj < ri);
        }
        ss[rank] = si; sidx[rank] = ri;
    }
    __syncthreads();
    // ---- Phase 2b: decode + clip ----
    for (int i = t; i < M; i += 256) {
        float4 b = decode_clip(prop, reg, sidx[i], ccol, wmax, hmax);
        bx4[i][0] = b.x; bx4[i][1] = b.y; bx4[i][2] = b.z; bx4[i][3] = b.w;
        supp[i] = 0;
    }
    __syncthreads();

    // ---- Phase 3+4: NMS + write kept keys to fixed per-class slots ----
    if (M <= 64) {
        // wave-ballot NMS on wave 0 (R7/R8/R9-validated): no barriers, no LDS traffic
        if (wv == 0) {
            const bool valid = lane < M;
            float b0 = 0, b1 = 0, b2 = 0, b3 = 0, sc = 0; int ri = 0;
            if (valid) { b0 = bx4[lane][0]; b1 = bx4[lane][1]; b2 = bx4[lane][2]; b3 = bx4[lane][3];
                         sc = ss[lane]; ri = sidx[lane]; }
            unsigned long long suppm = 0;
            for (int i = 0; i < M; ++i) {
                if ((suppm >> i) & 1ULL) continue;          // wave-uniform
                float ax1 = __shfl(b0, i), ay1 = __shfl(b1, i);
                float ax2 = __shfl(b2, i), ay2 = __shfl(b3, i);
                bool kill = valid && (lane > i) &&
                            (iou_legacy(ax1, ay1, ax2, ay2, b0, b1, b2, b3) > NMS_T);
                suppm |= __ballot(kill);
            }
            unsigned long long keepm = ~suppm;
            if (M < 64) keepm &= (1ULL << M) - 1ULL;
            if (valid && ((keepm >> lane) & 1ULL)) {
                int pos = __popcll(keepm & ((1ULL << lane) - 1ULL));
                dev_store_u64(&klist[(size_t)cidx * SLOTS + pos],
                              key_of(sc, (unsigned)(cidx * R_ROWS + ri)));
            }
            if (lane == 0) dev_store_i32(&kcount[cidx], __popcll(keepm));
        }
    } else {
        // fallback: sequential-i LDS NMS (block-uniform branch, barriers legal)
        for (int i = 0; i < M; i++) {
            if (!supp[i]) {
                float ax1 = bx4[i][0], ay1 = bx4[i][1], ax2 = bx4[i][2], ay2 = bx4[i][3];
                for (int j = i + 1 + t; j < M; j += 256) {
                    if (!supp[j]) {
                        float v = iou_legacy(ax1, ay1, ax2, ay2,
                                             bx4[j][0], bx4[j][1], bx4[j][2], bx4[j][3]);
                        if (v > NMS_T) supp[j] = 1;
                    }
                }
            }
            __syncthreads();
        }
        for (int i = t; i < M; i += 256) {
            if (!supp[i]) {
                int pos = 0;
                for (int j = 0; j < i; ++j) pos += !supp[j];
                dev_store_u64(&klist[(size_t)cidx * SLOTS + pos],
                              key_of(ss[i], (unsigned)(cidx * R_ROWS + sidx[i])));
            }
        }
        if (t == 0) {
            int kc = 0;
            for (int i = 0; i < M; ++i) kc += !supp[i];
            dev_store_i32(&kcount[cidx], kc);
        }
    }

    // ---- last-block handoff: RMW only (R7 lesson) ----
    __syncthreads();   // drains vmcnt(0): all sc1 stores at coherence point
    if (t == 0) sh_last = (atomicAdd(done, 1) == NBLK_CLS - 1) ? 1 : 0;
    __syncthreads();
    if (!sh_last) return;

    // ================= selector (exactly one block: the last to finish) =================
    if (t < NBLK_CLS) cs[t] = atomicAdd(&kcount[t], 0);   // RMW read: always fresh
    for (int b = t; b < NBINS; b += 256) hist_s[b] = 0;
    __syncthreads();
    if (t == 0) {
        int acc = 0;
        for (int c = 0; c < NBLK_CLS; ++c) { koff[c] = acc; acc += cs[c]; }
        koff[NBLK_CLS] = acc;
        sh_cut = 0; sh_mcnt = 0;
    }
    __syncthreads();
    const int K = koff[NBLK_CLS];
    const int target = (K < DETS) ? K : DETS;

    if (K <= CK_CAP) {
        // single sc1 sweep: keys -> LDS + LDS histogram
        for (int g = t; g < K; g += 256) {
            int c = find_class(koff, g);
            unsigned long long k = dev_load_u64(&klist[(size_t)c * SLOTS + (g - koff[c])]);
            ck[g] = k;
            atomicAdd(&hist_s[bin_of(key_score(k))], 1);
        }
        __syncthreads();

        // suffix scan of 1024 bins: S[b] = #keys with bin >= b
        int v0 = hist_s[4 * t], v1 = hist_s[4 * t + 1], v2 = hist_s[4 * t + 2], v3 = hist_s[4 * t + 3];
        int s3 = v3, s2 = v2 + s3, s1 = v1 + s2, s0 = v0 + s1;
        cs[t] = s0;
        __syncthreads();
        for (int off = 1; off < 256; off <<= 1) {
            int x = cs[t] + ((t + off < 256) ? cs[t + off] : 0);
            __syncthreads();
            cs[t] = x;
            __syncthreads();
        }
        int tail = (t < 255) ? cs[t + 1] : 0;
        int S0 = s0 + tail, S1 = s1 + tail, S2 = s2 + tail, S3 = s3 + tail;
        if (target > 0) {
            int best = -1;
            if      (S3 >= target) best = 4 * t + 3;
            else if (S2 >= target) best = 4 * t + 2;
            else if (S1 >= target) best = 4 * t + 1;
            else if (S0 >= target) best = 4 * t;
            if (best >= 0) atomicMax(&sh_cut, best);
        }
        __syncthreads();
        const int cut = sh_cut;   // survivors (bin >= cut) ⊇ top-target

        // compact survivors in-LDS
        for (int g = t; g < K; g += 256) {
            unsigned long long k = ck[g];
            if (bin_of(key_score(k)) >= cut) {
                int p = atomicAdd(&sh_mcnt, 1);
                if (p < SURV_CAP) cks[p] = k;
            }
        }
        __syncthreads();
        const int Mc = sh_mcnt;

        if (Mc <= SURV_CAP) {
            // exact rank among survivors (== global ranks; bijective -> direct scatter)
            int Mp = (Mc + 3) & ~3;
            if (t < Mp - Mc) cks[Mc + t] = 0;   // pad: key 0 never outranks a real key
            __syncthreads();
            for (int i = t; i < Mc; i += 256) {
                unsigned long long ki = cks[i];
                int r = 0;
                for (int j = 0; j < Mp; j += 4)
                    r += (int)(cks[j] > ki) + (int)(cks[j + 1] > ki)
                       + (int)(cks[j + 2] > ki) + (int)(cks[j + 3] > ki);
                if (r < DETS) {
                    sel_s[r] = key_score(ki);
                    sel_f[r] = key_flat(ki);
                }
            }
        } else {
            // degenerate tie flood: rank survivors against full ck (LDS, slower, correct)
            int Kp = (K + 3) & ~3;
            if (t < Kp - K) ck[K + t] = 0;
            __syncthreads();
            for (int g = t; g < K; g += 256) {
                unsigned long long ki = ck[g];
                if (bin_of(key_score(ki)) < cut) continue;
                int r = 0;
                for (int j = 0; j < Kp; j += 4)
                    r += (int)(ck[j] > ki) + (int)(ck[j + 1] > ki)
                       + (int)(ck[j + 2] > ki) + (int)(ck[j + 3] > ki);
                if (r < DETS) {
                    sel_s[r] = key_score(ki);
                    sel_f[r] = key_flat(ki);
                }
            }
        }
    } else {
        // K > CK_CAP (not reachable in practice): exact rank via global sc1 sweeps
        for (int g = t; g < K; g += 256) {
            int c = find_class(koff, g);
            unsigned long long ki = dev_load_u64(&klist[(size_t)c * SLOTS + (g - koff[c])]);
            int r = 0;
            for (int g2 = 0; g2 < K; ++g2) {
                int c2 = find_class(koff, g2);
                r += (int)(dev_load_u64(&klist[(size_t)c2 * SLOTS + (g2 - koff[c2])]) > ki);
            }
            if (r < DETS) {
                sel_s[r] = key_score(ki);
                sel_f[r] = key_flat(ki);
            }
        }
    }
    __syncthreads();

    // tail-fill (only when K < 100: then S[cut]==K so cks holds ALL kept keys)
    if (t == 0 && target < DETS) {
        int n = target, f = 0;
        while (n < DETS) {
            bool used = false;
            for (int q = 0; q < target; q++) if (key_flat(cks[q]) == f) { used = true; break; }
            if (!used) { sel_s[n] = NEG_S; sel_f[n] = f; n++; }
            f++;
        }
    }
    __syncthreads();

    // decode + write 600 outputs
    if (t < DETS) {
        int f = sel_f[t];
        int c2 = f / R_ROWS;
        int r  = f % R_ROWS;
        float4 b = decode_clip(prop, reg, r, c2 + 1, wmax, hmax);
        out[t] = sel_s[t];
        out[DETS + 4 * t + 0] = b.x;
        out[DETS + 4 * t + 1] = b.y;
        out[DETS + 4 * t + 2] = b.z;
        out[DETS + 4 * t + 3] = b.w;
        out[DETS * 5 + t] = (float)(c2 + 1);
    }
}

// ---------- host launcher ----------

extern "C" void kernel_launch(void* const* d_in, const int* in_sizes, int n_in,
                              void* d_out, int out_size, void* d_ws, size_t ws_size,
                              hipStream_t stream) {
    (void)in_sizes; (void)n_in; (void)out_size; (void)ws_size;
    const float* logits = (const float*)d_in[0];
    const float* reg    = (const float*)d_in[1];
    const float* prop   = (const float*)d_in[2];
    const int*   piw    = (const int*)d_in[3];
    const int*   pih    = (const int*)d_in[4];
    float* out = (float*)d_out;

    // workspace (bytes): done@0, kcount[80]@64, klist[80*1000 u64]@4096.
    // Only `done` needs zeroing each call (8B memset node, graph-legal, R8-proven);
    // kcount/klist are overwritten-before-read each call with deterministic values.
    char* ws = (char*)d_ws;
    int*   done    = (int*)(ws);
    int*   kcount  = (int*)(ws + 64);
    unsigned long long* klist = (unsigned long long*)(ws + 4096);

    hipMemsetAsync(ws, 0, 4, stream);
    k_all<<<dim3(NBLK_CLS), dim3(256), 0, stream>>>(logits, reg, prop, piw, pih,
                                                    klist, kcount, done, out);
}

// Round 11
// 38.829 us; speedup vs baseline: 2.6391x; 2.6391x over previous
//
#include <hip/hip_runtime.h>
#include <cmath>

#define R_ROWS 1000
#define NCLS   81
#define REGW   (NCLS * 4)
#define SCORE_T 0.05f
#define NMS_T   0.5f
#define NEG_S  -1e9f
#define DETS   100
#define CLIP_V 4.135166556742356f   // log(1000/16)
#define MAXC   1000
#define SLOTS  1000                  // per-class klist region
#define NBLK_CLS 80                  // classes 1..80 -> blocks 0..79

#define NBINS    1024
#define CK_CAP   2560                // LDS key buffer (typ. K ~ 2000)
#define SURV_CAP 512                 // LDS survivor buffer (typ. Mc ~ 150)

// ---------- exact-order helpers (no FMA contraction: match numpy/XLA separate rounding) ----------

__device__ __forceinline__ float4 decode_clip(const float* __restrict__ prop,
                                              const float* __restrict__ reg,
                                              int r, int ccol, float wmax, float hmax) {
    float x1 = prop[r * 4 + 0], y1 = prop[r * 4 + 1];
    float x2 = prop[r * 4 + 2], y2 = prop[r * 4 + 3];
    float w  = __fadd_rn(__fsub_rn(x2, x1), 1.0f);
    float h  = __fadd_rn(__fsub_rn(y2, y1), 1.0f);
    float cx = __fadd_rn(x1, __fmul_rn(0.5f, w));
    float cy = __fadd_rn(y1, __fmul_rn(0.5f, h));
    const float* rr = reg + r * REGW + 4 * ccol;
    float dx = rr[0] / 10.0f;
    float dy = rr[1] / 10.0f;
    float dw = fminf(rr[2] / 5.0f, CLIP_V);
    float dh = fminf(rr[3] / 5.0f, CLIP_V);
    float pcx = __fadd_rn(__fmul_rn(dx, w), cx);
    float pcy = __fadd_rn(__fmul_rn(dy, h), cy);
    float pw  = __fmul_rn(expf(dw), w);
    float ph  = __fmul_rn(expf(dh), h);
    float ox1 = __fsub_rn(pcx, __fmul_rn(0.5f, pw));
    float oy1 = __fsub_rn(pcy, __fmul_rn(0.5f, ph));
    float ox2 = __fsub_rn(__fadd_rn(pcx, __fmul_rn(0.5f, pw)), 1.0f);
    float oy2 = __fsub_rn(__fadd_rn(pcy, __fmul_rn(0.5f, ph)), 1.0f);
    float4 o;
    o.x = fminf(fmaxf(ox1, 0.0f), wmax);
    o.y = fminf(fmaxf(oy1, 0.0f), hmax);
    o.z = fminf(fmaxf(ox2, 0.0f), wmax);
    o.w = fminf(fmaxf(oy2, 0.0f), hmax);
    return o;
}

__device__ __forceinline__ float iou_legacy(float ax1, float ay1, float ax2, float ay2,
                                            float bx1, float by1, float bx2, float by2) {
    float aw = __fadd_rn(__fsub_rn(ax2, ax1), 1.0f);
    float ah = __fadd_rn(__fsub_rn(ay2, ay1), 1.0f);
    float areaA = __fmul_rn(aw, ah);
    float bw = __fadd_rn(__fsub_rn(bx2, bx1), 1.0f);
    float bh = __fadd_rn(__fsub_rn(by2, by1), 1.0f);
    float areaB = __fmul_rn(bw, bh);
    float ltx = fmaxf(ax1, bx1), lty = fmaxf(ay1, by1);
    float rbx = fminf(ax2, bx2), rby = fminf(ay2, by2);
    float wx = fmaxf(__fadd_rn(__fsub_rn(rbx, ltx), 1.0f), 0.0f);
    float wy = fmaxf(__fadd_rn(__fsub_rn(rby, lty), 1.0f), 0.0f);
    float inter = __fmul_rn(wx, wy);
    float denom = __fsub_rn(__fadd_rn(areaA, areaB), inter);
    return inter / denom;
}

// monotone coarse bin of a positive float score (positive IEEE bits are order-preserving)
__device__ __forceinline__ int bin_of(float s) {
    int idx = (int)(__float_as_uint(s) >> 16) - 0x3D00;   // scores in (0.05,1] -> [76,640]
    return idx < 0 ? 0 : (idx > NBINS - 1 ? NBINS - 1 : idx);
}

__device__ __forceinline__ unsigned long long key_of(float s, unsigned f) {
    // (score desc, flat asc) as one monotone u64; valid keys nonzero (score > 0.05)
    return ((unsigned long long)__float_as_uint(s) << 32) | (unsigned long long)(~f);
}
__device__ __forceinline__ float key_score(unsigned long long k) {
    return __uint_as_float((unsigned)(k >> 32));
}
__device__ __forceinline__ int key_flat(unsigned long long k) {
    return (int)(~(unsigned)k);
}

// upper-bound search: returns c with koff[c] <= g < koff[c+1]
__device__ __forceinline__ int find_class(const int* koff, int g) {
    int lo = 0, hi = NBLK_CLS;
    while (hi - lo > 1) { int mid = (lo + hi) >> 1; if (g >= koff[mid]) lo = mid; else hi = mid; }
    return lo;
}

// ---------- Kernel A: per-row softmax stats (1000-way parallel) ----------
// Plain stores; visibility to kernel B via dispatch-boundary release/acquire (R1-R9 proven).

__global__ __launch_bounds__(64) void k_stats(const float* __restrict__ logits,
                                              float* __restrict__ rowmax,
                                              float* __restrict__ rowsum) {
    int r = blockIdx.x;
    int l = threadIdx.x;
    float v1 = logits[r * NCLS + l];
    float v2 = (l < NCLS - 64) ? logits[r * NCLS + 64 + l] : -INFINITY;
    float m = fmaxf(v1, v2);
    #pragma unroll
    for (int off = 32; off; off >>= 1) m = fmaxf(m, __shfl_xor(m, off));
    float s = expf(__fsub_rn(v1, m));
    if (l < NCLS - 64) s = __fadd_rn(s, expf(__fsub_rn(v2, m)));
    #pragma unroll
    for (int off = 32; off; off >>= 1) s = __fadd_rn(s, __shfl_xor(s, off));
    if (l == 0) { rowmax[r] = m; rowsum[r] = s; }
}

// ---------- Kernel B: 80 class blocks — gather, sort, decode, NMS, slot writes ----------
// NO device atomics, NO sc1, NO handoff: plain stores to fixed per-class slots;
// kernel C (next dispatch) sees them via the dispatch boundary.

__global__ __launch_bounds__(256) void k_nms(const float* __restrict__ logits,
                                             const float* __restrict__ reg,
                                             const float* __restrict__ prop,
                                             const float* __restrict__ rowmax,
                                             const float* __restrict__ rowsum,
                                             const int* __restrict__ piw,
                                             const int* __restrict__ pih,
                                             unsigned long long* __restrict__ klist,
                                             int* __restrict__ kcount) {
    __shared__ float us[MAXC];  __shared__ int uidx[MAXC];
    __shared__ float ss[MAXC];  __shared__ int sidx[MAXC];
    __shared__ float bx4[MAXC][4];
    __shared__ int   supp[MAXC];
    __shared__ int   cnt;

    const int cidx = blockIdx.x;       // 0..79
    const int ccol = cidx + 1;         // skip background class 0
    const int t    = threadIdx.x;
    const int lane = t & 63;
    const int wv   = t >> 6;
    const float wmax = (float)(*piw - 1);
    const float hmax = (float)(*pih - 1);

    if (t == 0) cnt = 0;
    __syncthreads();

    // Phase 1: valid candidates (score > thresh), unsorted compaction into LDS
    for (int r = t; r < R_ROWS; r += 256) {
        float z = logits[r * NCLS + ccol];
        float s = expf(__fsub_rn(z, rowmax[r])) / rowsum[r];
        if (s > SCORE_T) {
            int p = atomicAdd(&cnt, 1);
            us[p] = s; uidx[p] = r;
        }
    }
    __syncthreads();
    const int M = cnt;

    // Phase 2a: exact rank sort (score desc, row asc)
    for (int i = t; i < M; i += 256) {
        float si = us[i]; int ri = uidx[i];
        int rank = 0;
        for (int j = 0; j < M; j++) {
            float sj = us[j]; int rj = uidx[j];
            rank += (sj > si) || (sj == si && rj < ri);
        }
        ss[rank] = si; sidx[rank] = ri;
    }
    __syncthreads();
    // Phase 2b: decode + clip
    for (int i = t; i < M; i += 256) {
        float4 b = decode_clip(prop, reg, sidx[i], ccol, wmax, hmax);
        bx4[i][0] = b.x; bx4[i][1] = b.y; bx4[i][2] = b.z; bx4[i][3] = b.w;
        supp[i] = 0;
    }
    __syncthreads();

    // Phase 3+4: NMS + write kept keys to fixed per-class slots (plain stores)
    if (M <= 64) {
        // wave-ballot NMS on wave 0 (validated R7-R10): no barriers, no LDS traffic
        if (wv == 0) {
            const bool valid = lane < M;
            float b0 = 0, b1 = 0, b2 = 0, b3 = 0, sc = 0; int ri = 0;
            if (valid) { b0 = bx4[lane][0]; b1 = bx4[lane][1]; b2 = bx4[lane][2]; b3 = bx4[lane][3];
                         sc = ss[lane]; ri = sidx[lane]; }
            unsigned long long suppm = 0;
            for (int i = 0; i < M; ++i) {
                if ((suppm >> i) & 1ULL) continue;          // wave-uniform
                float ax1 = __shfl(b0, i), ay1 = __shfl(b1, i);
                float ax2 = __shfl(b2, i), ay2 = __shfl(b3, i);
                bool kill = valid && (lane > i) &&
                            (iou_legacy(ax1, ay1, ax2, ay2, b0, b1, b2, b3) > NMS_T);
                suppm |= __ballot(kill);
            }
            unsigned long long keepm = ~suppm;
            if (M < 64) keepm &= (1ULL << M) - 1ULL;
            if (valid && ((keepm >> lane) & 1ULL)) {
                int pos = __popcll(keepm & ((1ULL << lane) - 1ULL));
                klist[(size_t)cidx * SLOTS + pos] = key_of(sc, (unsigned)(cidx * R_ROWS + ri));
            }
            if (lane == 0) kcount[cidx] = __popcll(keepm);
        }
    } else {
        // fallback: sequential-i LDS NMS (block-uniform branch, barriers legal)
        for (int i = 0; i < M; i++) {
            if (!supp[i]) {
                float ax1 = bx4[i][0], ay1 = bx4[i][1], ax2 = bx4[i][2], ay2 = bx4[i][3];
                for (int j = i + 1 + t; j < M; j += 256) {
                    if (!supp[j]) {
                        float v = iou_legacy(ax1, ay1, ax2, ay2,
                                             bx4[j][0], bx4[j][1], bx4[j][2], bx4[j][3]);
                        if (v > NMS_T) supp[j] = 1;
                    }
                }
            }
            __syncthreads();
        }
        for (int i = t; i < M; i += 256) {
            if (!supp[i]) {
                int pos = 0;
                for (int j = 0; j < i; ++j) pos += !supp[j];
                klist[(size_t)cidx * SLOTS + pos] = key_of(ss[i], (unsigned)(cidx * R_ROWS + sidx[i]));
            }
        }
        if (t == 0) {
            int kc = 0;
            for (int i = 0; i < M; ++i) kc += !supp[i];
            kcount[cidx] = kc;
        }
    }
}

// ---------- Kernel C: single block — histogram cutoff, rank, tail-fill, finalize ----------

__global__ __launch_bounds__(256) void k_select(const float* __restrict__ reg,
                                                const float* __restrict__ prop,
                                                const int* __restrict__ piw,
                                                const int* __restrict__ pih,
                                                const unsigned long long* __restrict__ klist,
                                                const int* __restrict__ kcount,
                                                float* __restrict__ out) {
    __shared__ int   koff[NBLK_CLS + 1];
    __shared__ int   cs[256];
    __shared__ int   hist_s[NBINS];
    __shared__ unsigned long long ck[CK_CAP + 4];
    __shared__ unsigned long long cks[SURV_CAP + 4];
    __shared__ float sel_s[DETS]; __shared__ int sel_f[DETS];
    __shared__ int   sh_cut, sh_mcnt;

    const int t = threadIdx.x;
    const float wmax = (float)(*piw - 1);
    const float hmax = (float)(*pih - 1);

    if (t < NBLK_CLS) cs[t] = kcount[t];
    for (int b = t; b < NBINS; b += 256) hist_s[b] = 0;
    __syncthreads();
    if (t == 0) {
        int acc = 0;
        for (int c = 0; c < NBLK_CLS; ++c) { koff[c] = acc; acc += cs[c]; }
        koff[NBLK_CLS] = acc;
        sh_cut = 0; sh_mcnt = 0;
    }
    __syncthreads();
    const int K = koff[NBLK_CLS];
    const int target = (K < DETS) ? K : DETS;

    if (K <= CK_CAP) {
        // single sweep: keys -> LDS + LDS histogram
        for (int g = t; g < K; g += 256) {
            int c = find_class(koff, g);
            unsigned long long k = klist[(size_t)c * SLOTS + (g - koff[c])];
            ck[g] = k;
            atomicAdd(&hist_s[bin_of(key_score(k))], 1);
        }
        __syncthreads();

        // suffix scan of 1024 bins: S[b] = #keys with bin >= b
        int v0 = hist_s[4 * t], v1 = hist_s[4 * t + 1], v2 = hist_s[4 * t + 2], v3 = hist_s[4 * t + 3];
        int s3 = v3, s2 = v2 + s3, s1 = v1 + s2, s0 = v0 + s1;
        cs[t] = s0;
        __syncthreads();
        for (int off = 1; off < 256; off <<= 1) {
            int x = cs[t] + ((t + off < 256) ? cs[t + off] : 0);
            __syncthreads();
            cs[t] = x;
            __syncthreads();
        }
        int tail = (t < 255) ? cs[t + 1] : 0;
        int S0 = s0 + tail, S1 = s1 + tail, S2 = s2 + tail, S3 = s3 + tail;
        if (target > 0) {
            int best = -1;
            if      (S3 >= target) best = 4 * t + 3;
            else if (S2 >= target) best = 4 * t + 2;
            else if (S1 >= target) best = 4 * t + 1;
            else if (S0 >= target) best = 4 * t;
            if (best >= 0) atomicMax(&sh_cut, best);
        }
        __syncthreads();
        const int cut = sh_cut;   // survivors (bin >= cut) ⊇ top-target

        // compact survivors in-LDS
        for (int g = t; g < K; g += 256) {
            unsigned long long k = ck[g];
            if (bin_of(key_score(k)) >= cut) {
                int p = atomicAdd(&sh_mcnt, 1);
                if (p < SURV_CAP) cks[p] = k;
            }
        }
        __syncthreads();
        const int Mc = sh_mcnt;

        if (Mc <= SURV_CAP) {
            // exact rank among survivors (== global ranks; bijective -> direct scatter)
            int Mp = (Mc + 3) & ~3;
            if (t < Mp - Mc) cks[Mc + t] = 0;   // pad: key 0 never outranks a real key
            __syncthreads();
            for (int i = t; i < Mc; i += 256) {
                unsigned long long ki = cks[i];
                int r = 0;
                for (int j = 0; j < Mp; j += 4)
                    r += (int)(cks[j] > ki) + (int)(cks[j + 1] > ki)
                       + (int)(cks[j + 2] > ki) + (int)(cks[j + 3] > ki);
                if (r < DETS) {
                    sel_s[r] = key_score(ki);
                    sel_f[r] = key_flat(ki);
                }
            }
        } else {
            // degenerate tie flood: rank survivors against full ck (LDS, slower, correct)
            int Kp = (K + 3) & ~3;
            if (t < Kp - K) ck[K + t] = 0;
            __syncthreads();
            for (int g = t; g < K; g += 256) {
                unsigned long long ki = ck[g];
                if (bin_of(key_score(ki)) < cut) continue;
                int r = 0;
                for (int j = 0; j < Kp; j += 4)
                    r += (int)(ck[j] > ki) + (int)(ck[j + 1] > ki)
                       + (int)(ck[j + 2] > ki) + (int)(ck[j + 3] > ki);
                if (r < DETS) {
                    sel_s[r] = key_score(ki);
                    sel_f[r] = key_flat(ki);
                }
            }
        }
    } else {
        // K > CK_CAP (not reachable in practice): exact rank via global sweeps
        for (int g = t; g < K; g += 256) {
            int c = find_class(koff, g);
            unsigned long long ki = klist[(size_t)c * SLOTS + (g - koff[c])];
            int r = 0;
            for (int g2 = 0; g2 < K; ++g2) {
                int c2 = find_class(koff, g2);
                r += (int)(klist[(size_t)c2 * SLOTS + (g2 - koff[c2])] > ki);
            }
            if (r < DETS) {
                sel_s[r] = key_score(ki);
                sel_f[r] = key_flat(ki);
            }
        }
    }
    __syncthreads();

    // tail-fill (only when K < 100: then cut==0, Mc==K, cks holds ALL kept keys)
    if (t == 0 && target < DETS) {
        int n = target, f = 0;
        while (n < DETS) {
            bool used = false;
            for (int q = 0; q < target; q++) if (key_flat(cks[q]) == f) { used = true; break; }
            if (!used) { sel_s[n] = NEG_S; sel_f[n] = f; n++; }
            f++;
        }
    }
    __syncthreads();

    // decode + write 600 outputs
    if (t < DETS) {
        int f = sel_f[t];
        int c2 = f / R_ROWS;
        int r  = f % R_ROWS;
        float4 b = decode_clip(prop, reg, r, c2 + 1, wmax, hmax);
        out[t] = sel_s[t];
        out[DETS + 4 * t + 0] = b.x;
        out[DETS + 4 * t + 1] = b.y;
        out[DETS + 4 * t + 2] = b.z;
        out[DETS + 4 * t + 3] = b.w;
        out[DETS * 5 + t] = (float)(c2 + 1);
    }
}

// ---------- host launcher ----------

extern "C" void kernel_launch(void* const* d_in, const int* in_sizes, int n_in,
                              void* d_out, int out_size, void* d_ws, size_t ws_size,
                              hipStream_t stream) {
    (void)in_sizes; (void)n_in; (void)out_size; (void)ws_size;
    const float* logits = (const float*)d_in[0];
    const float* reg    = (const float*)d_in[1];
    const float* prop   = (const float*)d_in[2];
    const int*   piw    = (const int*)d_in[3];
    const int*   pih    = (const int*)d_in[4];
    float* out = (float*)d_out;

    // workspace (bytes): kcount[80]@0, rowmax[1000]@1024, rowsum[1000]@5120,
    // klist[80*1000 u64]@12288. NOTHING needs zero-init: kcount/klist/rowmax/rowsum
    // are deterministically overwritten before being read, within this call's
    // dispatch chain (visibility via kernel-boundary release/acquire).
    char* ws = (char*)d_ws;
    int*   kcount  = (int*)(ws);
    float* rowmax  = (float*)(ws + 1024);
    float* rowsum  = (float*)(ws + 5120);
    unsigned long long* klist = (unsigned long long*)(ws + 12288);

    k_stats<<<dim3(R_ROWS), dim3(64), 0, stream>>>(logits, rowmax, rowsum);
    k_nms<<<dim3(NBLK_CLS), dim3(256), 0, stream>>>(logits, reg, prop, rowmax, rowsum,
                                                    piw, pih, klist, kcount);
    k_select<<<dim3(1), dim3(256), 0, stream>>>(reg, prop, piw, pih, klist, kcount, out);
}